// Round 8
// baseline (132.036 us; speedup 1.0000x reference)
//
#include <hip/hip_runtime.h>
#include <hip/hip_bf16.h>
#include <math.h>

// Problem constants
#define NB    4096
#define DH    784
#define KX8   832            // fp8 row bytes: 784 padded to 13*64
#define NSR   5
#define NNEG  (NB*NSR)       // 20480
#define NTOT  (NB + NNEG)    // 24576

#define A_CONST 1.576943f
#define PEXP    1.7901216f   // 2*B_PARAM
#define EPS_C   1.0e-4f
#define ALPHA_C 0.9296875f   // BATCH_COUNT=500: beta=0.5*(1-500/800)^2=0.0703125
#define BETA_C  0.0703125f

#define NBLK  528            // upper-triangular 32x32 block grid (8*66)
#define BUFB  8192           // LDS buffer stride in BYTES (128 rows x 64 B)

typedef __hip_bfloat16 bf16;
typedef short bf16x8 __attribute__((ext_vector_type(8)));
typedef float f32x4  __attribute__((ext_vector_type(4)));
typedef float f32x2  __attribute__((ext_vector_type(2)));
typedef long long2v __attribute__((ext_vector_type(2)));

// Workspace layout (bytes)
#define WS_XF8    0                      // 4096*832   = 3407872
#define WS_EBF    3407872                // 4096*32*2  = 262144
#define WS_SQX    3670016                // 4096*4     = 16384
#define WS_SQE    3686400                // 4096*4     = 16384
#define WS_ACC5   3702784                // 5*4096*4   = 81920  (atomic accumulators)
#define WS_UPART  8945664                // 96*4       = 384
#define WS_CNT    8946304                // 4

// ---- fused prep: blocks 0..1023 -> X cast to fp8-e4m3, COLUMN-PERMUTED layout
// (each 64B chunk stored as [q0h0|q0h1|q1h0|q1h1|...]: dest dword p in chunk c
// sources src float4 c*16 + h*8 + q*2 + w, q=p>>2, h=(p>>1)&1, w=p&1), + sqnorm;
// blocks 1024..1119 -> UMAP CE partials + e_to bf16 prep + zero acc5/cnt
__global__ void prep_fused(const float* __restrict__ X, const float* __restrict__ emb,
                           const int* __restrict__ perm, unsigned char* __restrict__ Xf8,
                           float* __restrict__ sqx, bf16* __restrict__ Ebf,
                           float* __restrict__ sqe, float* __restrict__ upart,
                           float* __restrict__ acc5, unsigned* __restrict__ cnt) {
    if (blockIdx.x == 0 && threadIdx.x == 0) *cnt = 0u;   // for gram last-block
    if (blockIdx.x < 1024) {
        const int wave = threadIdx.x >> 6, lane = threadIdx.x & 63;
        const int row = blockIdx.x * 4 + wave;
        const float4* xr = (const float4*)(X + (size_t)row * DH);
        int* xb = (int*)(Xf8 + (size_t)row * KX8);
        float s = 0.f;
        #pragma unroll
        for (int it = 0; it < 4; ++it) {
            const int idx = lane + it * 64;   // dest dword 0..207
            if (idx < 208) {
                const int c = idx >> 4, p = idx & 15;
                const int q = p >> 2, h = (p >> 1) & 1, w = p & 1;
                const int src = c * 16 + h * 8 + q * 2 + w;
                int pk = 0;
                if (src < 196) {
                    float4 v = xr[src];
                    s += v.x * v.x + v.y * v.y + v.z * v.z + v.w * v.w;
                    int lo = __builtin_amdgcn_cvt_pk_fp8_f32(v.x, v.y, 0, false);
                    pk = __builtin_amdgcn_cvt_pk_fp8_f32(v.z, v.w, lo, true);
                }
                xb[idx] = pk;
            }
        }
        #pragma unroll
        for (int off = 32; off; off >>= 1) s += __shfl_down(s, off, 64);
        if (lane == 0) sqx[row] = s;
        return;
    }
    // UMAP CE + e_to bf16 prep + acc5 zeroing
    const int ub = blockIdx.x - 1024;
    const int t = ub * 256 + threadIdx.x;
    if (t < 5 * NB) acc5[t] = 0.f;                // zero atomic accumulators
    float val = 0.f;
    if (t < NB) {
        const float4* av = (const float4*)(emb + (size_t)t * 32);
        float4 t0 = av[0], t1 = av[1], t2 = av[2], t3 = av[3];   // e_to
        float4 f0 = av[4], f1 = av[5], f2 = av[6], f3 = av[7];   // e_from
        bf16* eb = Ebf + (size_t)t * 32;
        union { bf16 h[4]; ushort4 u; } cv;
        #define ST4(dst, q) cv.h[0]=__float2bfloat16(q.x); cv.h[1]=__float2bfloat16(q.y); \
                            cv.h[2]=__float2bfloat16(q.z); cv.h[3]=__float2bfloat16(q.w); \
                            *(ushort4*)(dst) = cv.u;
        ST4(eb,      t0) ST4(eb + 4,  t1) ST4(eb + 8,  t2) ST4(eb + 12, t3)
        #undef ST4
        ushort4 z = {0, 0, 0, 0};
        *(ushort4*)(eb + 16) = z; *(ushort4*)(eb + 20) = z;
        *(ushort4*)(eb + 24) = z; *(ushort4*)(eb + 28) = z;
        sqe[t] = t0.x*t0.x + t0.y*t0.y + t0.z*t0.z + t0.w*t0.w
               + t1.x*t1.x + t1.y*t1.y + t1.z*t1.z + t1.w*t1.w
               + t2.x*t2.x + t2.y*t2.y + t2.z*t2.z + t2.w*t2.w
               + t3.x*t3.x + t3.y*t3.y + t3.z*t3.z + t3.w*t3.w;
        float d2 = 0.f;
        #define D2(a, b) { float4 df = {a.x-b.x, a.y-b.y, a.z-b.z, a.w-b.w}; \
                           d2 += df.x*df.x + df.y*df.y + df.z*df.z + df.w*df.w; }
        D2(t0, f0) D2(t1, f1) D2(t2, f2) D2(t3, f3)
        #undef D2
        float d = sqrtf(d2);
        float p = 1.f / (1.f + A_CONST * powf(d, PEXP));
        val = -logf(fminf(fmaxf(p, EPS_C), 1.f));
    } else if (t < NTOT) {
        const int k = t - NB;
        const int ti = k / 5;
        const int fi = perm[k] / 5;
        const float4* at = (const float4*)(emb + (size_t)ti * 32);
        const float4* bt = (const float4*)(emb + (size_t)fi * 32 + 16);
        float d2 = 0.f;
        #pragma unroll
        for (int q = 0; q < 4; ++q) {
            float4 a = at[q], b = bt[q];
            float4 df = {a.x-b.x, a.y-b.y, a.z-b.z, a.w-b.w};
            d2 += df.x*df.x + df.y*df.y + df.z*df.z + df.w*df.w;
        }
        float d = sqrtf(d2);
        float p = 1.f / (1.f + A_CONST * powf(d, PEXP));
        val = -logf(fminf(fmaxf(1.f - p, EPS_C), 1.f));
    }
    #pragma unroll
    for (int off = 32; off; off >>= 1) val += __shfl_down(val, off, 64);
    __shared__ float ps[4];
    if ((threadIdx.x & 63) == 0) ps[threadIdx.x >> 6] = val;
    __syncthreads();
    if (threadIdx.x == 0) upart[ub] = ps[0] + ps[1] + ps[2] + ps[3];
}

// ---- main: upper-triangular 128x128 fp8 X-gram.
// Round-8 (base = round-6, 44.7us verified): two changes.
// (1) TRANSPORT: global_load_lds DMA (common to every 44-49us variant; R7
//     showed the wall is not sync/traffic/footprint) replaced by reg-staging:
//     2x global_load_dwordx4/thread with 2-stage lead in named reg banks
//     (static parity indexing), then 2x ds_write_b128. ONE lgkmcnt(0)+
//     s_barrier per stage (write(t+1) and read(t-1) of the same buffer are
//     barrier-separated; write(t)->read(t) protected by lgkmcnt(0)+barrier).
// (2) RESIDENCY: LDS 67.6->48.1 KB (2 bufs + scr overlay) and
//     __launch_bounds__(512,6) (VGPR<=84) -> 3 blocks/CU -> capacity 768 >=
//     528 -> the grid runs in ONE round instead of two (occupancy data says
//     all prior variants ran ~2 sequential rounds of ~22-26us).
// E-operands direct from global (bytes identical to the LDS path; verified).
// Epilogue/atomics/region-mapping/last-block fold: byte-identical to round 6.
__global__ __launch_bounds__(512, 6) void gram_kernel(
    const unsigned char* __restrict__ Xf8, const bf16* __restrict__ Ebf,
    const float* __restrict__ sqx, const float* __restrict__ sqe,
    float* __restrict__ acc5, const float* __restrict__ upart,
    unsigned* __restrict__ cnt, float* __restrict__ out) {
    __shared__ __align__(16) unsigned char smem[48128];
    unsigned char* As = smem;                       // 2*BUFB = 16384
    unsigned char* Bs = smem + 2 * BUFB;            // 2*BUFB (end 32768)
    float* scr  = (float*)smem;                     // epilogue scratch (<=46080 B)
    float* sqxs = (float*)(smem + 46080);           // 256 f: [0..127]=i, [128..255]=j
    float* sqes = (float*)(smem + 47104);           // 256 f

    // Region-based XCD mapping (XCD = blockIdx & 7, idx = blockIdx >> 3):
    //  k<6 : square S(g,h), pairs {01,02,03,12,13,23}; idx<64 -> (g*8+idx/8,
    //        h*8+idx%8); idx 64,65 -> donated diag cell (panel in footprint).
    //  k=6 : D0 ranks 0..33 then D1 ranks 0..31; k=7 : D2 0..35 then D3 0..29.
    int bi, bj;
    {
        const int k = blockIdx.x & 7;
        const int idx = blockIdx.x >> 3;          // 0..65
        int g = -1, r = 0;
        if (k < 6) {
            const int SG[6] = {0,0,0,1,1,2}, SH[6] = {1,2,3,2,3,3};
            if (idx < 64) { bi = SG[k]*8 + (idx>>3); bj = SH[k]*8 + (idx&7); }
            else {
                const int DG[6] = {1,0,3,1,3,3};
                const int DR[6] = {32,34,30,34,32,34};
                g = DG[k]; r = DR[k] + (idx - 64);
            }
        } else if (k == 6) {
            if (idx < 34) { g = 0; r = idx; } else { g = 1; r = idx - 34; }
        } else {
            if (idx < 36) { g = 2; r = idx; } else { g = 3; r = idx - 36; }
        }
        if (g >= 0) {   // unrank within 8x8 upper triangle (incl diagonal)
            int a = 0;
            while (r >= 8 - a) { r -= 8 - a; ++a; }
            bi = g * 8 + a; bj = g * 8 + a + r;
        }
    }
    const int i0 = bi * 128, j0 = bj * 128;

    const int tid  = threadIdx.x;
    const int wave = tid >> 6;
    const int lane = tid & 63;
    const int wy = wave >> 1, wx = wave & 1;        // wy 0..3: 32-row strip; wx 0..1: 64-col half
    const int quad = lane >> 4, l15 = lane & 15;

    f32x4 acc[2][4];
    #pragma unroll
    for (int a = 0; a < 2; ++a)
        #pragma unroll
        for (int b = 0; b < 4; ++b)
            acc[a][b] = (f32x4){0.f, 0.f, 0.f, 0.f};

    // staging geometry (identical LDS image to round 6): wave w owns chunk w
    // (16 rows) of A and of B; lane L: row w*16 + (L>>2), pre-swizzled global
    // 16-B seg (L&3)^((L>>3)&3); LDS dest = wave*1024 + lane*16.
    const int rA  = lane >> 2;
    const int gsb = (((lane & 3) ^ ((lane >> 3) & 3))) * 16;
    const unsigned char* gA = Xf8 + (size_t)(i0 + wave * 16 + rA) * KX8 + gsb;
    const unsigned char* gB = Xf8 + (size_t)(j0 + wave * 16 + rA) * KX8 + gsb;
    const int woff = wave * 1024 + (lane << 4);

    // sq-norm staging + one full sync BEFORE any prefetch loads are issued.
    if (tid < 128) {
        sqxs[tid] = sqx[i0 + tid]; sqxs[128 + tid] = sqx[j0 + tid];
        sqes[tid] = sqe[i0 + tid]; sqes[128 + tid] = sqe[j0 + tid];
    }
    __syncthreads();

    // prologue: load stages 0,1 into reg banks; write stage 0 to buf0.
    long2v aBk[2], bBk[2];
    aBk[0] = *(const long2v*)(gA);      bBk[0] = *(const long2v*)(gB);
    aBk[1] = *(const long2v*)(gA + 64); bBk[1] = *(const long2v*)(gB + 64);
    *(long2v*)(As + woff) = aBk[0];
    *(long2v*)(Bs + woff) = bBk[0];

    // fragment byte offset: 16B = [h0 8B | h1 8B] for this lane's quad
    // (column-permuted layout), at swizzled position quad^key.
    const int key = (l15 >> 1) & 3;
    const int boX = ((quad ^ key) << 4);

    #pragma unroll
    for (int t = 0; t < 13; ++t) {
        // own ds_writes (stage t) complete, then block-wide barrier: buf[t&1]
        // is readable by all waves. (Single barrier/stage: write(t+1) below is
        // after this barrier; last reads of that buffer were at iter t-1
        // before THIS barrier -> separated.)
        asm volatile("s_waitcnt lgkmcnt(0)" ::: "memory");
        __builtin_amdgcn_s_barrier();
        const unsigned char* bufA = As + (t & 1) * BUFB;
        const unsigned char* bufB = Bs + (t & 1) * BUFB;
        long2v aF[2], bF[4];
        #pragma unroll
        for (int mi = 0; mi < 2; ++mi)
            aF[mi] = *(const long2v*)(bufA + (wy * 32 + mi * 16 + l15) * 64 + boX);
        #pragma unroll
        for (int ni = 0; ni < 4; ++ni)
            bF[ni] = *(const long2v*)(bufB + (wx * 64 + ni * 16 + l15) * 64 + boX);
        if (t + 2 < 13) {             // issue stage t+2 loads into bank t&1
            aBk[t & 1] = *(const long2v*)(gA + (t + 2) * 64);
            bBk[t & 1] = *(const long2v*)(gB + (t + 2) * 64);
        }
        #pragma unroll
        for (int mi = 0; mi < 2; ++mi)
            #pragma unroll
            for (int ni = 0; ni < 4; ++ni) {
                acc[mi][ni] = __builtin_amdgcn_mfma_f32_16x16x32_fp8_fp8(
                    aF[mi][0], bF[ni][0], acc[mi][ni], 0, 0, 0);
                acc[mi][ni] = __builtin_amdgcn_mfma_f32_16x16x32_fp8_fp8(
                    aF[mi][1], bF[ni][1], acc[mi][ni], 0, 0, 0);
            }
        if (t + 1 < 13) {             // write stage t+1 into buf[(t+1)&1]
            *(long2v*)(As + ((t + 1) & 1) * BUFB + woff) = aBk[(t + 1) & 1];
            *(long2v*)(Bs + ((t + 1) & 1) * BUFB + woff) = bBk[(t + 1) & 1];
        }
    }

    // E fragments DIRECT from global (bytes identical to the old LDS path:
    // swizzle cancels -> addr = row*64 + quad*16).
    const unsigned char* Eb = (const unsigned char*)Ebf;
    bf16x8 afE[2], bfrE[4];
    #pragma unroll
    for (int mi = 0; mi < 2; ++mi)
        afE[mi] = *(const bf16x8*)(Eb + (size_t)(i0 + wy * 32 + mi * 16 + l15) * 64 + quad * 16);
    #pragma unroll
    for (int ni = 0; ni < 4; ++ni)
        bfrE[ni] = *(const bf16x8*)(Eb + (size_t)(j0 + wx * 64 + ni * 16 + l15) * 64 + quad * 16);
    float sqxj[4], sqej[4];
    #pragma unroll
    for (int ni = 0; ni < 4; ++ni) {
        const int jl = wx * 64 + ni * 16 + l15;
        sqxj[ni] = sqxs[128 + jl]; sqej[ni] = sqes[128 + jl];
    }
    __syncthreads();   // all waves past K-loop -> scr region free

    // C/D layout: col = lane&15, row = quad*4 + reg  [m89/m91]
    float cst[4][5];   // col partials per ni: {H, H2, L, L2, HL}, both mi
    #pragma unroll
    for (int ni = 0; ni < 4; ++ni)
        #pragma unroll
        for (int c = 0; c < 5; ++c) cst[ni][c] = 0.f;

    #pragma unroll
    for (int mi = 0; mi < 2; ++mi) {
        f32x4 aE[4];
        #pragma unroll
        for (int ni = 0; ni < 4; ++ni) {
            f32x4 z = (f32x4){0.f, 0.f, 0.f, 0.f};
            aE[ni] = __builtin_amdgcn_mfma_f32_16x16x32_bf16(afE[mi], bfrE[ni], z, 0, 0, 0);
        }
        const int ilb = wy * 32 + mi * 16 + quad * 4;
        float sqxi[4], sqei[4];
        #pragma unroll
        for (int r = 0; r < 4; ++r) { sqxi[r] = sqxs[ilb + r]; sqei[r] = sqes[ilb + r]; }
        float rs[5][4];
        #pragma unroll
        for (int c = 0; c < 5; ++c)
            #pragma unroll
            for (int r = 0; r < 4; ++r) rs[c][r] = 0.f;
        #pragma unroll
        for (int ni = 0; ni < 4; ++ni) {
            const int j = j0 + wx * 64 + ni * 16 + l15;
            #pragma unroll
            for (int r = 0; r < 4; ++r) {
                const int i = i0 + ilb + r;
                float H, L;
                if (i == j) { H = 0.f; L = 0.f; }
                else {
                    float d2  = sqxi[r] + sqxj[ni] - 2.0f * acc[mi][ni][r];
                    H = sqrtf(fmaxf(d2, 0.f));
                    float d2e = sqei[r] + sqej[ni] - 2.0f * aE[ni][r];
                    L = sqrtf(fmaxf(d2e, 0.f));
                }
                rs[0][r] += H; rs[1][r] += H * H; rs[2][r] += L;
                rs[3][r] += L * L; rs[4][r] += H * L;
                cst[ni][0] += H; cst[ni][1] += H * H; cst[ni][2] += L;
                cst[ni][3] += L * L; cst[ni][4] += H * L;
            }
        }
        // dump row partials: [ (wx*5+c)*64 + li ]*18 + l15, li = wy*16+quad*4+r.
        // write banks: (72*quad + l15) & 31 = (8q+l15)&31 -> 2-way (free).
        #pragma unroll
        for (int c = 0; c < 5; ++c)
            #pragma unroll
            for (int r = 0; r < 4; ++r)
                scr[(size_t)((((wx * 5 + c) << 6) + (wy << 4) + (quad << 2) + r)) * 18 + l15]
                    = rs[c][r];
        __syncthreads();
        // cooperative 16-wide reduce over BOTH wx halves -> one atomic per elem
        for (int o = tid; o < 320; o += 512) {
            const int c = o >> 6, li = o & 63;
            const float* p0 = scr + (size_t)((c << 6) + li) * 18;          // wx=0
            const float* p1 = scr + (size_t)(((5 + c) << 6) + li) * 18;    // wx=1
            float s = 0.f;
            #pragma unroll
            for (int k = 0; k < 16; k += 2) {
                f32x2 v0 = *(const f32x2*)&p0[k]; s += v0.x + v0.y;
                f32x2 v1 = *(const f32x2*)&p1[k]; s += v1.x + v1.y;
            }
            const int iloc = ((li >> 4) << 5) + mi * 16 + (li & 15);
            unsafeAtomicAdd(&acc5[(size_t)c * NB + (i0 + iloc)], s);
        }
        __syncthreads();
    }

    if (bi != bj) {
        // dump col partials: [ (c*128 + j) ]*17 + wy*4+quad; ~2-way banks.
        #pragma unroll
        for (int ni = 0; ni < 4; ++ni) {
            const int jl = wx * 64 + ni * 16 + l15;
            #pragma unroll
            for (int c = 0; c < 5; ++c)
                scr[(size_t)(c * 128 + jl) * 17 + (wy << 2) + quad] = cst[ni][c];
        }
        __syncthreads();
        for (int o = tid; o < 640; o += 512) {
            const int c = o >> 7, j = o & 127;
            const float* p = scr + (size_t)(c * 128 + j) * 17;
            float s = (((p[0] + p[1]) + (p[2] + p[3])) + ((p[4] + p[5]) + (p[6] + p[7])))
                    + (((p[8] + p[9]) + (p[10] + p[11])) + ((p[12] + p[13]) + (p[14] + p[15])));
            unsafeAtomicAdd(&acc5[(size_t)c * NB + (j0 + j)], s);
        }
    }

    // ---- last-block fold: per-row corr from acc5 + upart -> out
    __shared__ int lastFlag;
    __syncthreads();                           // all threads' atomics issued+drained
    if (tid == 0) {
        __threadfence();                       // our adds visible device-wide
        lastFlag = (atomicAdd(cnt, 1u) == (unsigned)(NBLK - 1));
    }
    __syncthreads();
    if (lastFlag) {
        __threadfence();                       // acquire all blocks' atomic adds
        const float invN = 1.0f / (float)NB;
        float v = 0.f;
        #pragma unroll
        for (int rr = 0; rr < 8; ++rr) {
            const int r = tid + rr * 512;
            const float a  = acc5[0 * NB + r];
            const float b  = acc5[1 * NB + r];
            const float c2 = acc5[2 * NB + r];
            const float d  = acc5[3 * NB + r];
            const float e  = acc5[4 * NB + r];
            float num = e - a * c2 * invN;
            float vh  = fmaxf(b - a * a * invN, 0.f);
            float vl  = fmaxf(d - c2 * c2 * invN, 0.f);
            v += num / (sqrtf(vh) * sqrtf(vl));
        }
        v *= (-BETA_C * invN);
        if (tid < 96) v += upart[tid] * (ALPHA_C / (float)NTOT);
        #pragma unroll
        for (int off = 32; off; off >>= 1) v += __shfl_down(v, off, 64);
        float* fin = (float*)smem;             // scr free here
        __syncthreads();
        if ((tid & 63) == 0) fin[tid >> 6] = v;
        __syncthreads();
        if (tid == 0)
            out[0] = ((fin[0] + fin[1]) + (fin[2] + fin[3]))
                   + ((fin[4] + fin[5]) + (fin[6] + fin[7]));
    }
}

extern "C" void kernel_launch(void* const* d_in, const int* in_sizes, int n_in,
                              void* d_out, int out_size, void* d_ws, size_t ws_size,
                              hipStream_t stream) {
    const float* emb  = (const float*)d_in[0];   // (4096, 32) f32
    const float* ph   = (const float*)d_in[1];   // (4096, 784) f32
    const int*   perm = (const int*)d_in[2];     // (20480,) i32
    float* out = (float*)d_out;

    char* ws = (char*)d_ws;
    unsigned char* Xf8 = (unsigned char*)(ws + WS_XF8);
    bf16*  Ebf    = (bf16*) (ws + WS_EBF);
    float* sqx    = (float*)(ws + WS_SQX);
    float* sqe    = (float*)(ws + WS_SQE);
    float* acc5   = (float*)(ws + WS_ACC5);
    float* upart  = (float*)(ws + WS_UPART);
    unsigned* cnt = (unsigned*)(ws + WS_CNT);

    prep_fused<<<1120, 256, 0, stream>>>(ph, emb, perm, Xf8, sqx, Ebf, sqe, upart, acc5, cnt);
    gram_kernel<<<NBLK, 512, 0, stream>>>(Xf8, Ebf, sqx, sqe, acc5, upart, cnt, out);
}

// Round 9
// 119.336 us; speedup vs baseline: 1.1064x; 1.1064x over previous
//
#include <hip/hip_runtime.h>
#include <hip/hip_bf16.h>
#include <math.h>

// Problem constants
#define NB    4096
#define DH    784
#define KX8   832            // fp8 row bytes: 784 padded to 13*64
#define NSR   5
#define NNEG  (NB*NSR)       // 20480
#define NTOT  (NB + NNEG)    // 24576

#define A_CONST 1.576943f
#define PEXP    1.7901216f   // 2*B_PARAM
#define EPS_C   1.0e-4f
#define ALPHA_C 0.9296875f   // BATCH_COUNT=500: beta=0.5*(1-500/800)^2=0.0703125
#define BETA_C  0.0703125f

#define NBLK  528            // upper-triangular 32x32 block grid (8*66)
#define BUFB  16384          // LDS stage stride: A 8KB + B 8KB

typedef __hip_bfloat16 bf16;
typedef short bf16x8 __attribute__((ext_vector_type(8)));
typedef float f32x4  __attribute__((ext_vector_type(4)));
typedef float f32x2  __attribute__((ext_vector_type(2)));
typedef long long2v __attribute__((ext_vector_type(2)));

// Workspace layout (bytes)
#define WS_XF8    0                      // 4096*832   = 3407872
#define WS_EBF    3407872                // 4096*32*2  = 262144
#define WS_SQX    3670016                // 4096*4     = 16384
#define WS_SQE    3686400                // 4096*4     = 16384
#define WS_ACC5   3702784                // 5*4096*4   = 81920  (atomic accumulators)
#define WS_UPART  8945664                // 96*4       = 384
#define WS_CNT    8946304                // 4

__device__ __forceinline__ void gl2lds16(const void* g, void* l) {
    __builtin_amdgcn_global_load_lds(
        (const __attribute__((address_space(1))) unsigned int*)g,
        (__attribute__((address_space(3))) unsigned int*)l,
        16, 0, 0);
}

// ---- fused prep: blocks 0..1023 -> X cast to fp8-e4m3, COLUMN-PERMUTED layout
// (each 64B chunk stored as [q0h0|q0h1|q1h0|q1h1|...]: dest dword p in chunk c
// sources src float4 c*16 + h*8 + q*2 + w, q=p>>2, h=(p>>1)&1, w=p&1), + sqnorm;
// blocks 1024..1119 -> UMAP CE partials + e_to bf16 prep + zero acc5/cnt
__global__ void prep_fused(const float* __restrict__ X, const float* __restrict__ emb,
                           const int* __restrict__ perm, unsigned char* __restrict__ Xf8,
                           float* __restrict__ sqx, bf16* __restrict__ Ebf,
                           float* __restrict__ sqe, float* __restrict__ upart,
                           float* __restrict__ acc5, unsigned* __restrict__ cnt) {
    if (blockIdx.x == 0 && threadIdx.x == 0) *cnt = 0u;   // for gram last-block
    if (blockIdx.x < 1024) {
        const int wave = threadIdx.x >> 6, lane = threadIdx.x & 63;
        const int row = blockIdx.x * 4 + wave;
        const float4* xr = (const float4*)(X + (size_t)row * DH);
        int* xb = (int*)(Xf8 + (size_t)row * KX8);
        float s = 0.f;
        #pragma unroll
        for (int it = 0; it < 4; ++it) {
            const int idx = lane + it * 64;   // dest dword 0..207
            if (idx < 208) {
                const int c = idx >> 4, p = idx & 15;
                const int q = p >> 2, h = (p >> 1) & 1, w = p & 1;
                const int src = c * 16 + h * 8 + q * 2 + w;
                int pk = 0;
                if (src < 196) {
                    float4 v = xr[src];
                    s += v.x * v.x + v.y * v.y + v.z * v.z + v.w * v.w;
                    int lo = __builtin_amdgcn_cvt_pk_fp8_f32(v.x, v.y, 0, false);
                    pk = __builtin_amdgcn_cvt_pk_fp8_f32(v.z, v.w, lo, true);
                }
                xb[idx] = pk;
            }
        }
        #pragma unroll
        for (int off = 32; off; off >>= 1) s += __shfl_down(s, off, 64);
        if (lane == 0) sqx[row] = s;
        return;
    }
    // UMAP CE + e_to bf16 prep + acc5 zeroing
    const int ub = blockIdx.x - 1024;
    const int t = ub * 256 + threadIdx.x;
    if (t < 5 * NB) acc5[t] = 0.f;                // zero atomic accumulators
    float val = 0.f;
    if (t < NB) {
        const float4* av = (const float4*)(emb + (size_t)t * 32);
        float4 t0 = av[0], t1 = av[1], t2 = av[2], t3 = av[3];   // e_to
        float4 f0 = av[4], f1 = av[5], f2 = av[6], f3 = av[7];   // e_from
        bf16* eb = Ebf + (size_t)t * 32;
        union { bf16 h[4]; ushort4 u; } cv;
        #define ST4(dst, q) cv.h[0]=__float2bfloat16(q.x); cv.h[1]=__float2bfloat16(q.y); \
                            cv.h[2]=__float2bfloat16(q.z); cv.h[3]=__float2bfloat16(q.w); \
                            *(ushort4*)(dst) = cv.u;
        ST4(eb,      t0) ST4(eb + 4,  t1) ST4(eb + 8,  t2) ST4(eb + 12, t3)
        #undef ST4
        ushort4 z = {0, 0, 0, 0};
        *(ushort4*)(eb + 16) = z; *(ushort4*)(eb + 20) = z;
        *(ushort4*)(eb + 24) = z; *(ushort4*)(eb + 28) = z;
        sqe[t] = t0.x*t0.x + t0.y*t0.y + t0.z*t0.z + t0.w*t0.w
               + t1.x*t1.x + t1.y*t1.y + t1.z*t1.z + t1.w*t1.w
               + t2.x*t2.x + t2.y*t2.y + t2.z*t2.z + t2.w*t2.w
               + t3.x*t3.x + t3.y*t3.y + t3.z*t3.z + t3.w*t3.w;
        float d2 = 0.f;
        #define D2(a, b) { float4 df = {a.x-b.x, a.y-b.y, a.z-b.z, a.w-b.w}; \
                           d2 += df.x*df.x + df.y*df.y + df.z*df.z + df.w*df.w; }
        D2(t0, f0) D2(t1, f1) D2(t2, f2) D2(t3, f3)
        #undef D2
        float d = sqrtf(d2);
        float p = 1.f / (1.f + A_CONST * powf(d, PEXP));
        val = -logf(fminf(fmaxf(p, EPS_C), 1.f));
    } else if (t < NTOT) {
        const int k = t - NB;
        const int ti = k / 5;
        const int fi = perm[k] / 5;
        const float4* at = (const float4*)(emb + (size_t)ti * 32);
        const float4* bt = (const float4*)(emb + (size_t)fi * 32 + 16);
        float d2 = 0.f;
        #pragma unroll
        for (int q = 0; q < 4; ++q) {
            float4 a = at[q], b = bt[q];
            float4 df = {a.x-b.x, a.y-b.y, a.z-b.z, a.w-b.w};
            d2 += df.x*df.x + df.y*df.y + df.z*df.z + df.w*df.w;
        }
        float d = sqrtf(d2);
        float p = 1.f / (1.f + A_CONST * powf(d, PEXP));
        val = -logf(fminf(fmaxf(1.f - p, EPS_C), 1.f));
    }
    #pragma unroll
    for (int off = 32; off; off >>= 1) val += __shfl_down(val, off, 64);
    __shared__ float ps[4];
    if ((threadIdx.x & 63) == 0) ps[threadIdx.x >> 6] = val;
    __syncthreads();
    if (threadIdx.x == 0) upart[ub] = ps[0] + ps[1] + ps[2] + ps[3];
}

// ---- main: upper-triangular 128x128 fp8 X-gram.
// Round-9: ONE-ROUND RESIDENCY. All prior non-spilling variants ran as
// ~2 sequential rounds of ~22-26us blocks (capacity 2 blocks/CU x 256 < 528).
// This config: 256 threads / 4 waves (each wave 64x64, acc[4][4]), round-6
// transport (global_load_lds, 3-buffer depth-2, per-stage vmcnt(4)+barrier),
// LDS = 3x16KB + 2KB norms = 51.2KB -> 3 blocks/CU -> capacity 768 >= 528
// -> one round. Occupancy capped via LDS, NOT launch_bounds (round-8 lesson:
// VGPR cap 40 -> spill -> FETCH 42MB/WRITE 78MB/85us). E-operands direct
// from global (bytes identical; E-stage deleted -> uniform vmcnt(4)).
// Epilogue = round-7 256-thread version with its j-norm bug FIXED (stages
// both i- and j-side norms). Atomics/region-map/last-block fold unchanged.
__global__ __launch_bounds__(256, 3) void gram_kernel(
    const unsigned char* __restrict__ Xf8, const bf16* __restrict__ Ebf,
    const float* __restrict__ sqx, const float* __restrict__ sqe,
    float* __restrict__ acc5, const float* __restrict__ upart,
    unsigned* __restrict__ cnt, float* __restrict__ out) {
    __shared__ __align__(16) unsigned char smem[51200];
    unsigned char* As = smem;                       // 3 stages x 8KB A
    unsigned char* Bs = smem + 3 * 8192;            // 3 stages x 8KB B (end 49152)
    float* sqxs = (float*)(smem + 49152);           // 256 f: [0..127]=i, [128..255]=j
    float* sqes = (float*)(smem + 50176);           // 256 f
    float* scr  = (float*)smem;                     // epilogue scratch (<=23040 B)

    // Region-based XCD mapping (XCD = blockIdx & 7, idx = blockIdx >> 3):
    //  k<6 : square S(g,h), pairs {01,02,03,12,13,23}; idx<64 -> (g*8+idx/8,
    //        h*8+idx%8); idx 64,65 -> donated diag cell (panel in footprint).
    //  k=6 : D0 ranks 0..33 then D1 ranks 0..31; k=7 : D2 0..35 then D3 0..29.
    int bi, bj;
    {
        const int k = blockIdx.x & 7;
        const int idx = blockIdx.x >> 3;          // 0..65
        int g = -1, r = 0;
        if (k < 6) {
            const int SG[6] = {0,0,0,1,1,2}, SH[6] = {1,2,3,2,3,3};
            if (idx < 64) { bi = SG[k]*8 + (idx>>3); bj = SH[k]*8 + (idx&7); }
            else {
                const int DG[6] = {1,0,3,1,3,3};
                const int DR[6] = {32,34,30,34,32,34};
                g = DG[k]; r = DR[k] + (idx - 64);
            }
        } else if (k == 6) {
            if (idx < 34) { g = 0; r = idx; } else { g = 1; r = idx - 34; }
        } else {
            if (idx < 36) { g = 2; r = idx; } else { g = 3; r = idx - 36; }
        }
        if (g >= 0) {   // unrank within 8x8 upper triangle (incl diagonal)
            int a = 0;
            while (r >= 8 - a) { r -= 8 - a; ++a; }
            bi = g * 8 + a; bj = g * 8 + a + r;
        }
    }
    const int i0 = bi * 128, j0 = bj * 128;

    const int tid  = threadIdx.x;
    const int wave = tid >> 6;
    const int lane = tid & 63;
    const int wy = wave >> 1, wx = wave & 1;        // wy: 64-row half, wx: 64-col half
    const int quad = lane >> 4, l15 = lane & 15;

    f32x4 acc[4][4];
    #pragma unroll
    for (int a = 0; a < 4; ++a)
        #pragma unroll
        for (int b = 0; b < 4; ++b)
            acc[a][b] = (f32x4){0.f, 0.f, 0.f, 0.f};

    // staging: 8 chunks of 16 rows per side; wave w stages chunks {2w,2w+1}
    // of A and of B (4 DMAs/thread/stage). lane L: row chunk*16 + (L>>2),
    // pre-swizzled global seg (L&3)^((L>>3)&3); linear LDS dest (required).
    const int rA  = lane >> 2;
    const int gsb = (((lane & 3) ^ ((lane >> 3) & 3))) * 16;
    const unsigned char* gA0 = Xf8 + (size_t)(i0 + wave * 32 + rA) * KX8 + gsb;
    const unsigned char* gA1 = Xf8 + (size_t)(i0 + wave * 32 + 16 + rA) * KX8 + gsb;
    const unsigned char* gB0 = Xf8 + (size_t)(j0 + wave * 32 + rA) * KX8 + gsb;
    const unsigned char* gB1 = Xf8 + (size_t)(j0 + wave * 32 + 16 + rA) * KX8 + gsb;

    // sq-norm staging (BOTH i and j sides), one full sync BEFORE any DMA.
    if (tid < 128) {
        sqxs[tid] = sqx[i0 + tid]; sqxs[128 + tid] = sqx[j0 + tid];
        sqes[tid] = sqe[i0 + tid]; sqes[128 + tid] = sqe[j0 + tid];
    }
    __syncthreads();

#define STAGE_X(buf) { \
        unsigned char* la = As + (buf) * 8192 + wave * 2048; \
        unsigned char* lb = Bs + (buf) * 8192 + wave * 2048; \
        gl2lds16(gA0, la); gl2lds16(gA1, la + 1024); \
        gl2lds16(gB0, lb); gl2lds16(gB1, lb + 1024); \
        gA0 += 64; gA1 += 64; gB0 += 64; gB1 += 64; }

    // prologue: stages 0,1 -> bufs 0,1 (8 DMAs/thread in flight)
    STAGE_X(0)
    STAGE_X(1)

    // fragment byte offset: 16B = [h0 8B | h1 8B] for this lane's quad
    // (column-permuted layout), at swizzled position quad^key.
    const int key = (l15 >> 1) & 3;
    const int boX = ((quad ^ key) << 4);

    #pragma unroll
    for (int t = 0; t < 13; ++t) {
        // retire stage t's 4 DMAs (leave stage t+1's 4 in flight); t==12: drain.
        if (t < 12) { asm volatile("s_waitcnt vmcnt(4)" ::: "memory"); }
        else        { asm volatile("s_waitcnt vmcnt(0)" ::: "memory"); }
        __builtin_amdgcn_s_barrier();
        const int cur = (t % 3) * 8192;
        if (t < 11) { const int nb = ((t + 2) % 3); STAGE_X(nb) }
        long2v aF[4], bF[4];
        #pragma unroll
        for (int mi = 0; mi < 4; ++mi)
            aF[mi] = *(const long2v*)&As[cur + (wy * 64 + mi * 16 + l15) * 64 + boX];
        #pragma unroll
        for (int ni = 0; ni < 4; ++ni)
            bF[ni] = *(const long2v*)&Bs[cur + (wx * 64 + ni * 16 + l15) * 64 + boX];
        #pragma unroll
        for (int mi = 0; mi < 4; ++mi)
            #pragma unroll
            for (int ni = 0; ni < 4; ++ni) {
                acc[mi][ni] = __builtin_amdgcn_mfma_f32_16x16x32_fp8_fp8(
                    aF[mi][0], bF[ni][0], acc[mi][ni], 0, 0, 0);
                acc[mi][ni] = __builtin_amdgcn_mfma_f32_16x16x32_fp8_fp8(
                    aF[mi][1], bF[ni][1], acc[mi][ni], 0, 0, 0);
            }
    }
#undef STAGE_X

    // E fragments DIRECT from global (bytes identical to the LDS path:
    // swizzle cancels -> addr = row*64 + quad*16).
    const unsigned char* Eb = (const unsigned char*)Ebf;
    bf16x8 afE[4], bfrE[4];
    #pragma unroll
    for (int mi = 0; mi < 4; ++mi)
        afE[mi] = *(const bf16x8*)(Eb + (size_t)(i0 + wy * 64 + mi * 16 + l15) * 64 + quad * 16);
    #pragma unroll
    for (int ni = 0; ni < 4; ++ni)
        bfrE[ni] = *(const bf16x8*)(Eb + (size_t)(j0 + wx * 64 + ni * 16 + l15) * 64 + quad * 16);
    float sqxj[4], sqej[4];
    #pragma unroll
    for (int ni = 0; ni < 4; ++ni) {
        const int jl = wx * 64 + ni * 16 + l15;
        sqxj[ni] = sqxs[128 + jl]; sqej[ni] = sqes[128 + jl];   // j-side norms
    }
    __syncthreads();   // all waves past K-loop -> scr region free

    // C/D layout: col = lane&15, row = quad*4 + reg  [m89/m91]
    float cst[4][5];   // col partials per ni: {H, H2, L, L2, HL}, over all mi
    #pragma unroll
    for (int ni = 0; ni < 4; ++ni)
        #pragma unroll
        for (int c = 0; c < 5; ++c) cst[ni][c] = 0.f;

    #pragma unroll
    for (int mi = 0; mi < 4; ++mi) {
        f32x4 aE[4];
        #pragma unroll
        for (int ni = 0; ni < 4; ++ni) {
            f32x4 z = (f32x4){0.f, 0.f, 0.f, 0.f};
            aE[ni] = __builtin_amdgcn_mfma_f32_16x16x32_bf16(afE[mi], bfrE[ni], z, 0, 0, 0);
        }
        const int ilb = wy * 64 + mi * 16 + quad * 4;   // local row base 0..127
        float sqxi[4], sqei[4];
        #pragma unroll
        for (int r = 0; r < 4; ++r) { sqxi[r] = sqxs[ilb + r]; sqei[r] = sqes[ilb + r]; }
        float rs[5][4];
        #pragma unroll
        for (int c = 0; c < 5; ++c)
            #pragma unroll
            for (int r = 0; r < 4; ++r) rs[c][r] = 0.f;
        #pragma unroll
        for (int ni = 0; ni < 4; ++ni) {
            const int j = j0 + wx * 64 + ni * 16 + l15;
            #pragma unroll
            for (int r = 0; r < 4; ++r) {
                const int i = i0 + ilb + r;
                float H, L;
                if (i == j) { H = 0.f; L = 0.f; }
                else {
                    float d2  = sqxi[r] + sqxj[ni] - 2.0f * acc[mi][ni][r];
                    H = sqrtf(fmaxf(d2, 0.f));
                    float d2e = sqei[r] + sqej[ni] - 2.0f * aE[ni][r];
                    L = sqrtf(fmaxf(d2e, 0.f));
                }
                rs[0][r] += H; rs[1][r] += H * H; rs[2][r] += L;
                rs[3][r] += L * L; rs[4][r] += H * L;
                cst[ni][0] += H; cst[ni][1] += H * H; cst[ni][2] += L;
                cst[ni][3] += L * L; cst[ni][4] += H * L;
            }
        }
        // dump row partials: [ (wx*5+c)*32 + li ]*18 + l15, li = wy*16+quad*4+r
        // (2-way bank aliasing: (72q + l15)&31 = (8q+l15)&31 -> free).
        #pragma unroll
        for (int c = 0; c < 5; ++c)
            #pragma unroll
            for (int r = 0; r < 4; ++r)
                scr[(size_t)((((wx * 5 + c) << 5) + (wy << 4) + (quad << 2) + r)) * 18 + l15]
                    = rs[c][r];
        __syncthreads();
        // cooperative 16-wide reduce over BOTH wx halves -> one atomic per elem
        for (int o = tid; o < 160; o += 256) {
            const int c = o >> 5, li = o & 31;
            const float* p0 = scr + (size_t)((c << 5) + li) * 18;          // wx=0
            const float* p1 = scr + (size_t)(((5 + c) << 5) + li) * 18;    // wx=1
            float s = 0.f;
            #pragma unroll
            for (int k = 0; k < 16; k += 2) {
                f32x2 v0 = *(const f32x2*)&p0[k]; s += v0.x + v0.y;
                f32x2 v1 = *(const f32x2*)&p1[k]; s += v1.x + v1.y;
            }
            const int iloc = ((li >> 4) << 6) + mi * 16 + (li & 15);
            unsafeAtomicAdd(&acc5[(size_t)c * NB + (i0 + iloc)], s);
        }
        __syncthreads();
    }

    if (bi != bj) {
        // dump col partials: [ (c*128 + jl) ]*9 + wy*4+quad (8 contributors/col)
        #pragma unroll
        for (int ni = 0; ni < 4; ++ni) {
            const int jl = wx * 64 + ni * 16 + l15;
            #pragma unroll
            for (int c = 0; c < 5; ++c)
                scr[(size_t)(c * 128 + jl) * 9 + (wy << 2) + quad] = cst[ni][c];
        }
        __syncthreads();
        for (int o = tid; o < 640; o += 256) {
            const int c = o >> 7, j = o & 127;
            const float* p = scr + (size_t)(c * 128 + j) * 9;
            float s = ((p[0] + p[1]) + (p[2] + p[3])) + ((p[4] + p[5]) + (p[6] + p[7]));
            unsafeAtomicAdd(&acc5[(size_t)c * NB + (j0 + j)], s);
        }
    }

    // ---- last-block fold: per-row corr from acc5 + upart -> out
    __shared__ int lastFlag;
    __syncthreads();                           // all threads' atomics issued+drained
    if (tid == 0) {
        __threadfence();                       // our adds visible device-wide
        lastFlag = (atomicAdd(cnt, 1u) == (unsigned)(NBLK - 1));
    }
    __syncthreads();
    if (lastFlag) {
        __threadfence();                       // acquire all blocks' atomic adds
        const float invN = 1.0f / (float)NB;
        float v = 0.f;
        #pragma unroll
        for (int rr = 0; rr < 16; ++rr) {
            const int r = tid + rr * 256;
            const float a  = acc5[0 * NB + r];
            const float b  = acc5[1 * NB + r];
            const float c2 = acc5[2 * NB + r];
            const float d  = acc5[3 * NB + r];
            const float e  = acc5[4 * NB + r];
            float num = e - a * c2 * invN;
            float vh  = fmaxf(b - a * a * invN, 0.f);
            float vl  = fmaxf(d - c2 * c2 * invN, 0.f);
            v += num / (sqrtf(vh) * sqrtf(vl));
        }
        v *= (-BETA_C * invN);
        if (tid < 96) v += upart[tid] * (ALPHA_C / (float)NTOT);
        #pragma unroll
        for (int off = 32; off; off >>= 1) v += __shfl_down(v, off, 64);
        float* fin = (float*)smem;             // scr free here
        __syncthreads();
        if ((tid & 63) == 0) fin[tid >> 6] = v;
        __syncthreads();
        if (tid == 0)
            out[0] = (fin[0] + fin[1]) + (fin[2] + fin[3]);
    }
}

extern "C" void kernel_launch(void* const* d_in, const int* in_sizes, int n_in,
                              void* d_out, int out_size, void* d_ws, size_t ws_size,
                              hipStream_t stream) {
    const float* emb  = (const float*)d_in[0];   // (4096, 32) f32
    const float* ph   = (const float*)d_in[1];   // (4096, 784) f32
    const int*   perm = (const int*)d_in[2];     // (20480,) i32
    float* out = (float*)d_out;

    char* ws = (char*)d_ws;
    unsigned char* Xf8 = (unsigned char*)(ws + WS_XF8);
    bf16*  Ebf    = (bf16*) (ws + WS_EBF);
    float* sqx    = (float*)(ws + WS_SQX);
    float* sqe    = (float*)(ws + WS_SQE);
    float* acc5   = (float*)(ws + WS_ACC5);
    float* upart  = (float*)(ws + WS_UPART);
    unsigned* cnt = (unsigned*)(ws + WS_CNT);

    prep_fused<<<1120, 256, 0, stream>>>(ph, emb, perm, Xf8, sqx, Ebf, sqe, upart, acc5, cnt);
    gram_kernel<<<NBLK, 256, 0, stream>>>(Xf8, Ebf, sqx, sqe, acc5, upart, cnt, out);
}

// Round 10
// 108.024 us; speedup vs baseline: 1.2223x; 1.1047x over previous
//
#include <hip/hip_runtime.h>
#include <hip/hip_bf16.h>
#include <math.h>

// Problem constants
#define NB    4096
#define DH    784
#define NSR   5
#define NNEG  (NB*NSR)       // 20480
#define NTOT  (NB + NNEG)    // 24576

#define A_CONST 1.576943f
#define PEXP    1.7901216f   // 2*B_PARAM
#define EPS_C   1.0e-4f
#define ALPHA_C 0.9296875f   // BATCH_COUNT=500: beta=0.5*(1-500/800)^2=0.0703125
#define BETA_C  0.0703125f

#define NBLK  528            // upper-triangular 32x32 block grid (8*66)
#define BUFB  8192           // LDS buffer stride in BYTES (128 rows x 64 B)
#define CH    262144         // K-chunk stride in XT layout: 4096 rows x 64 B

typedef __hip_bfloat16 bf16;
typedef short bf16x8 __attribute__((ext_vector_type(8)));
typedef float f32x4  __attribute__((ext_vector_type(4)));
typedef float f32x2  __attribute__((ext_vector_type(2)));
typedef long long2v __attribute__((ext_vector_type(2)));

// Workspace layout (bytes)
#define WS_XF8    0                      // 13*4096*64 = 3407872 (K-MAJOR: XT[c][row][64B])
#define WS_EBF    3407872                // 4096*32*2  = 262144
#define WS_SQX    3670016                // 4096*4     = 16384
#define WS_SQE    3686400                // 4096*4     = 16384
#define WS_ACC5   3702784                // 5*4096*4   = 81920  (atomic accumulators)
#define WS_UPART  8945664                // 96*4       = 384
#define WS_CNT    8946304                // 4

__device__ __forceinline__ void gl2lds16(const void* g, void* l) {
    __builtin_amdgcn_global_load_lds(
        (const __attribute__((address_space(1))) unsigned int*)g,
        (__attribute__((address_space(3))) unsigned int*)l,
        16, 0, 0);
}

// ---- fused prep: blocks 0..1023 -> X cast to fp8-e4m3, K-MAJOR layout
// XT[c][row][p]: dword index c*65536 + row*16 + p  (c=0..12 K-chunks, p=0..15).
// Within a chunk the 16 dwords keep the COLUMN-PERMUTED order: dword p
// sources src float4 c*16 + h*8 + q*2 + w, q=p>>2, h=(p>>1)&1, w=p&1.
// Round-10 change: only the STORAGE of the chunks moved (row-major -> K-major)
// so gram's staging instructions read contiguous 1KB. Bytes per (row,chunk)
// identical. blocks 1024..1119 -> UMAP CE partials + e_to bf16 prep + zeroing.
__global__ void prep_fused(const float* __restrict__ X, const float* __restrict__ emb,
                           const int* __restrict__ perm, unsigned char* __restrict__ Xf8,
                           float* __restrict__ sqx, bf16* __restrict__ Ebf,
                           float* __restrict__ sqe, float* __restrict__ upart,
                           float* __restrict__ acc5, unsigned* __restrict__ cnt) {
    if (blockIdx.x == 0 && threadIdx.x == 0) *cnt = 0u;   // for gram last-block
    if (blockIdx.x < 1024) {
        const int wave = threadIdx.x >> 6, lane = threadIdx.x & 63;
        const int row = blockIdx.x * 4 + wave;
        const float4* xr = (const float4*)(X + (size_t)row * DH);
        int* xb = (int*)Xf8;
        float s = 0.f;
        #pragma unroll
        for (int it = 0; it < 4; ++it) {
            const int idx = lane + it * 64;   // dword 0..207
            if (idx < 208) {
                const int c = idx >> 4, p = idx & 15;
                const int q = p >> 2, h = (p >> 1) & 1, w = p & 1;
                const int src = c * 16 + h * 8 + q * 2 + w;
                int pk = 0;
                if (src < 196) {
                    float4 v = xr[src];
                    s += v.x * v.x + v.y * v.y + v.z * v.z + v.w * v.w;
                    int lo = __builtin_amdgcn_cvt_pk_fp8_f32(v.x, v.y, 0, false);
                    pk = __builtin_amdgcn_cvt_pk_fp8_f32(v.z, v.w, lo, true);
                }
                xb[(size_t)c * 65536 + (size_t)row * 16 + p] = pk;   // K-major
            }
        }
        #pragma unroll
        for (int off = 32; off; off >>= 1) s += __shfl_down(s, off, 64);
        if (lane == 0) sqx[row] = s;
        return;
    }
    // UMAP CE + e_to bf16 prep + acc5 zeroing
    const int ub = blockIdx.x - 1024;
    const int t = ub * 256 + threadIdx.x;
    if (t < 5 * NB) acc5[t] = 0.f;                // zero atomic accumulators
    float val = 0.f;
    if (t < NB) {
        const float4* av = (const float4*)(emb + (size_t)t * 32);
        float4 t0 = av[0], t1 = av[1], t2 = av[2], t3 = av[3];   // e_to
        float4 f0 = av[4], f1 = av[5], f2 = av[6], f3 = av[7];   // e_from
        bf16* eb = Ebf + (size_t)t * 32;
        union { bf16 h[4]; ushort4 u; } cv;
        #define ST4(dst, q) cv.h[0]=__float2bfloat16(q.x); cv.h[1]=__float2bfloat16(q.y); \
                            cv.h[2]=__float2bfloat16(q.z); cv.h[3]=__float2bfloat16(q.w); \
                            *(ushort4*)(dst) = cv.u;
        ST4(eb,      t0) ST4(eb + 4,  t1) ST4(eb + 8,  t2) ST4(eb + 12, t3)
        #undef ST4
        ushort4 z = {0, 0, 0, 0};
        *(ushort4*)(eb + 16) = z; *(ushort4*)(eb + 20) = z;
        *(ushort4*)(eb + 24) = z; *(ushort4*)(eb + 28) = z;
        sqe[t] = t0.x*t0.x + t0.y*t0.y + t0.z*t0.z + t0.w*t0.w
               + t1.x*t1.x + t1.y*t1.y + t1.z*t1.z + t1.w*t1.w
               + t2.x*t2.x + t2.y*t2.y + t2.z*t2.z + t2.w*t2.w
               + t3.x*t3.x + t3.y*t3.y + t3.z*t3.z + t3.w*t3.w;
        float d2 = 0.f;
        #define D2(a, b) { float4 df = {a.x-b.x, a.y-b.y, a.z-b.z, a.w-b.w}; \
                           d2 += df.x*df.x + df.y*df.y + df.z*df.z + df.w*df.w; }
        D2(t0, f0) D2(t1, f1) D2(t2, f2) D2(t3, f3)
        #undef D2
        float d = sqrtf(d2);
        float p = 1.f / (1.f + A_CONST * powf(d, PEXP));
        val = -logf(fminf(fmaxf(p, EPS_C), 1.f));
    } else if (t < NTOT) {
        const int k = t - NB;
        const int ti = k / 5;
        const int fi = perm[k] / 5;
        const float4* at = (const float4*)(emb + (size_t)ti * 32);
        const float4* bt = (const float4*)(emb + (size_t)fi * 32 + 16);
        float d2 = 0.f;
        #pragma unroll
        for (int q = 0; q < 4; ++q) {
            float4 a = at[q], b = bt[q];
            float4 df = {a.x-b.x, a.y-b.y, a.z-b.z, a.w-b.w};
            d2 += df.x*df.x + df.y*df.y + df.z*df.z + df.w*df.w;
        }
        float d = sqrtf(d2);
        float p = 1.f / (1.f + A_CONST * powf(d, PEXP));
        val = -logf(fminf(fmaxf(1.f - p, EPS_C), 1.f));
    }
    #pragma unroll
    for (int off = 32; off; off >>= 1) val += __shfl_down(val, off, 64);
    __shared__ float ps[4];
    if ((threadIdx.x & 63) == 0) ps[threadIdx.x >> 6] = val;
    __syncthreads();
    if (threadIdx.x == 0) upart[ub] = ps[0] + ps[1] + ps[2] + ps[3];
}

// ---- main: upper-triangular 128x128 fp8 X-gram.
// Round-10 (base = round-6 champion, 44.7us): ONE change -- Xf8 is K-MAJOR,
// so each staging instruction's 64 lanes cover rows [w*16,w*16+16) x 64B =
// CONTIGUOUS 1KB (was 16 scattered 64B segments across 13KB -> 16 txns/inst).
// Rate audit: our staging ran 18.6 GB/s/CU vs ~500 GB/s/CU for the identical
// m97 structure with contiguous addresses -- scatter is the last untested
// candidate for the per-stage wall. Schedule/epilogue byte-identical to R6.
__global__ __launch_bounds__(512, 4) void gram_kernel(
    const unsigned char* __restrict__ Xf8, const bf16* __restrict__ Ebf,
    const float* __restrict__ sqx, const float* __restrict__ sqe,
    float* __restrict__ acc5, const float* __restrict__ upart,
    unsigned* __restrict__ cnt, float* __restrict__ out) {
    __shared__ __align__(16) unsigned char smem[67584];
    unsigned char* As = smem;                       // 4*BUFB = 32768
    unsigned char* Bs = smem + 4 * BUFB;            // 4*BUFB = 32768 (end 65536)
    float* sqxs = (float*)(smem + 65536);           // 256 f: [0..127]=i, [128..255]=j
    float* sqes = (float*)(smem + 66560);           // 256 f
    float* scr  = (float*)smem;                     // epilogue scratch (<=46080 B)

    // Region-based XCD mapping (XCD = blockIdx & 7, idx = blockIdx >> 3):
    //  k<6 : square S(g,h), pairs {01,02,03,12,13,23}; idx<64 -> (g*8+idx/8,
    //        h*8+idx%8); idx 64,65 -> donated diag cell (panel in footprint).
    //  k=6 : D0 ranks 0..33 then D1 ranks 0..31; k=7 : D2 0..35 then D3 0..29.
    int bi, bj;
    {
        const int k = blockIdx.x & 7;
        const int idx = blockIdx.x >> 3;          // 0..65
        int g = -1, r = 0;
        if (k < 6) {
            const int SG[6] = {0,0,0,1,1,2}, SH[6] = {1,2,3,2,3,3};
            if (idx < 64) { bi = SG[k]*8 + (idx>>3); bj = SH[k]*8 + (idx&7); }
            else {
                const int DG[6] = {1,0,3,1,3,3};
                const int DR[6] = {32,34,30,34,32,34};
                g = DG[k]; r = DR[k] + (idx - 64);
            }
        } else if (k == 6) {
            if (idx < 34) { g = 0; r = idx; } else { g = 1; r = idx - 34; }
        } else {
            if (idx < 36) { g = 2; r = idx; } else { g = 3; r = idx - 36; }
        }
        if (g >= 0) {   // unrank within 8x8 upper triangle (incl diagonal)
            int a = 0;
            while (r >= 8 - a) { r -= 8 - a; ++a; }
            bi = g * 8 + a; bj = g * 8 + a + r;
        }
    }
    const int i0 = bi * 128, j0 = bj * 128;

    const int tid  = threadIdx.x;
    const int wave = tid >> 6;
    const int lane = tid & 63;
    const int wy = wave >> 1, wx = wave & 1;        // wy 0..3: 32-row strip; wx 0..1: 64-col half
    const int quad = lane >> 4, l15 = lane & 15;

    f32x4 acc[2][4];
    #pragma unroll
    for (int a = 0; a < 2; ++a)
        #pragma unroll
        for (int b = 0; b < 4; ++b)
            acc[a][b] = (f32x4){0.f, 0.f, 0.f, 0.f};

    // staging: 8 chunks of 16 rows; wave w stages chunk w of A and of B.
    // lane L: row w*16 + (L>>2); 16-B seg (L&3)^((L>>3)&3) (pre-swizzled
    // source, linear LDS dest). K-major: one instruction = 1KB CONTIGUOUS.
    const int rA  = lane >> 2;
    const int gsb = (((lane & 3) ^ ((lane >> 3) & 3))) * 16;
    const unsigned char* gA = Xf8 + (size_t)(i0 + wave * 16 + rA) * 64 + gsb;
    const unsigned char* gB = Xf8 + (size_t)(j0 + wave * 16 + rA) * 64 + gsb;

    // sq-norm staging FIRST, then one full __syncthreads (its vmcnt(0) drain
    // happens before any DMA is in flight).
    if (tid < 128) {
        sqxs[tid] = sqx[i0 + tid]; sqxs[128 + tid] = sqx[j0 + tid];
        sqes[tid] = sqe[i0 + tid]; sqes[128 + tid] = sqe[j0 + tid];
    }
    __syncthreads();

    // prologue: prefetch stages 0..2 (buffers 0..2); 2 loads/thread/stage
    #pragma unroll
    for (int s = 0; s < 3; ++s) {
        gl2lds16(gA, As + s * BUFB + wave * 1024);
        gl2lds16(gB, Bs + s * BUFB + wave * 1024);
        gA += CH; gB += CH;
    }

    // fragment byte offset: 16B = [h0 8B | h1 8B] for this lane's quad
    // (column-permuted layout), at swizzled position quad^key.
    const int key = (l15 >> 1) & 3;
    const int boX = ((quad ^ key) << 4);

    #pragma unroll
    for (int t = 0; t < 13; ++t) {
        // wait ONLY this stage's 2 DMAs (leaves stages t+1, t+2 in flight).
        // Outstanding before wait: t<=11 -> 6; t==12 -> 4 (s12,E) -> vmcnt(2).
        if (t < 12) { asm volatile("s_waitcnt vmcnt(4)" ::: "memory"); }
        else        { asm volatile("s_waitcnt vmcnt(2)" ::: "memory"); }
        __builtin_amdgcn_s_barrier();
        const int cur = (t & 3) * BUFB;
        const int nb  = ((t + 3) & 3) * BUFB;
        if (t < 10) {                 // prefetch X stage t+3
            gl2lds16(gA, As + nb + wave * 1024);
            gl2lds16(gB, Bs + nb + wave * 1024);
            gA += CH; gB += CH;
        } else if (t == 10) {         // prefetch E (stage 13) into buf 13%4 = 1
            gl2lds16((const unsigned char*)(Ebf + (size_t)(i0 + wave * 16 + rA) * 32) + gsb,
                     As + BUFB + wave * 1024);
            gl2lds16((const unsigned char*)(Ebf + (size_t)(j0 + wave * 16 + rA) * 32) + gsb,
                     Bs + BUFB + wave * 1024);
        }                             // t >= 11: nothing left to prefetch
        long2v aF[2], bF[4];
        #pragma unroll
        for (int mi = 0; mi < 2; ++mi)
            aF[mi] = *(const long2v*)&As[cur + (wy * 32 + mi * 16 + l15) * 64 + boX];
        #pragma unroll
        for (int ni = 0; ni < 4; ++ni)
            bF[ni] = *(const long2v*)&Bs[cur + (wx * 64 + ni * 16 + l15) * 64 + boX];
        #pragma unroll
        for (int mi = 0; mi < 2; ++mi)
            #pragma unroll
            for (int ni = 0; ni < 4; ++ni) {
                acc[mi][ni] = __builtin_amdgcn_mfma_f32_16x16x32_fp8_fp8(
                    aF[mi][0], bF[ni][0], acc[mi][ni], 0, 0, 0);
                acc[mi][ni] = __builtin_amdgcn_mfma_f32_16x16x32_fp8_fp8(
                    aF[mi][1], bF[ni][1], acc[mi][ni], 0, 0, 0);
            }
    }
    // E stage (buf 1): drain remaining DMA, sync all waves.
    asm volatile("s_waitcnt vmcnt(0)" ::: "memory");
    __builtin_amdgcn_s_barrier();

    // E fragments + j-side norms into registers BEFORE scratch overwrites As/Bs.
    bf16x8 afE[2], bfrE[4];
    #pragma unroll
    for (int mi = 0; mi < 2; ++mi)
        afE[mi] = *(const bf16x8*)&As[BUFB + (wy * 32 + mi * 16 + l15) * 64 + boX];
    #pragma unroll
    for (int ni = 0; ni < 4; ++ni)
        bfrE[ni] = *(const bf16x8*)&Bs[BUFB + (wx * 64 + ni * 16 + l15) * 64 + boX];
    float sqxj[4], sqej[4];
    #pragma unroll
    for (int ni = 0; ni < 4; ++ni) {
        const int jl = wx * 64 + ni * 16 + l15;
        sqxj[ni] = sqxs[128 + jl]; sqej[ni] = sqes[128 + jl];
    }
    __syncthreads();   // all waves done reading E tiles -> scratch region free

    // C/D layout: col = lane&15, row = quad*4 + reg  [m89/m91]
    float cst[4][5];   // col partials per ni: {H, H2, L, L2, HL}, both mi
    #pragma unroll
    for (int ni = 0; ni < 4; ++ni)
        #pragma unroll
        for (int c = 0; c < 5; ++c) cst[ni][c] = 0.f;

    #pragma unroll
    for (int mi = 0; mi < 2; ++mi) {
        f32x4 aE[4];
        #pragma unroll
        for (int ni = 0; ni < 4; ++ni) {
            f32x4 z = (f32x4){0.f, 0.f, 0.f, 0.f};
            aE[ni] = __builtin_amdgcn_mfma_f32_16x16x32_bf16(afE[mi], bfrE[ni], z, 0, 0, 0);
        }
        const int ilb = wy * 32 + mi * 16 + quad * 4;
        float sqxi[4], sqei[4];
        #pragma unroll
        for (int r = 0; r < 4; ++r) { sqxi[r] = sqxs[ilb + r]; sqei[r] = sqes[ilb + r]; }
        float rs[5][4];
        #pragma unroll
        for (int c = 0; c < 5; ++c)
            #pragma unroll
            for (int r = 0; r < 4; ++r) rs[c][r] = 0.f;
        #pragma unroll
        for (int ni = 0; ni < 4; ++ni) {
            const int j = j0 + wx * 64 + ni * 16 + l15;
            #pragma unroll
            for (int r = 0; r < 4; ++r) {
                const int i = i0 + ilb + r;
                float H, L;
                if (i == j) { H = 0.f; L = 0.f; }
                else {
                    float d2  = sqxi[r] + sqxj[ni] - 2.0f * acc[mi][ni][r];
                    H = sqrtf(fmaxf(d2, 0.f));
                    float d2e = sqei[r] + sqej[ni] - 2.0f * aE[ni][r];
                    L = sqrtf(fmaxf(d2e, 0.f));
                }
                rs[0][r] += H; rs[1][r] += H * H; rs[2][r] += L;
                rs[3][r] += L * L; rs[4][r] += H * L;
                cst[ni][0] += H; cst[ni][1] += H * H; cst[ni][2] += L;
                cst[ni][3] += L * L; cst[ni][4] += H * L;
            }
        }
        // dump row partials: [ (wx*5+c)*64 + li ]*18 + l15, li = wy*16+quad*4+r.
        // write banks: (72*quad + l15) & 31 = (8q+l15)&31 -> 2-way (free).
        #pragma unroll
        for (int c = 0; c < 5; ++c)
            #pragma unroll
            for (int r = 0; r < 4; ++r)
                scr[(size_t)((((wx * 5 + c) << 6) + (wy << 4) + (quad << 2) + r)) * 18 + l15]
                    = rs[c][r];
        __syncthreads();
        // cooperative 16-wide reduce over BOTH wx halves -> one atomic per elem
        for (int o = tid; o < 320; o += 512) {
            const int c = o >> 6, li = o & 63;
            const float* p0 = scr + (size_t)((c << 6) + li) * 18;          // wx=0
            const float* p1 = scr + (size_t)(((5 + c) << 6) + li) * 18;    // wx=1
            float s = 0.f;
            #pragma unroll
            for (int k = 0; k < 16; k += 2) {
                f32x2 v0 = *(const f32x2*)&p0[k]; s += v0.x + v0.y;
                f32x2 v1 = *(const f32x2*)&p1[k]; s += v1.x + v1.y;
            }
            const int iloc = ((li >> 4) << 5) + mi * 16 + (li & 15);
            unsafeAtomicAdd(&acc5[(size_t)c * NB + (i0 + iloc)], s);
        }
        __syncthreads();
    }

    if (bi != bj) {
        // dump col partials: [ (c*128 + j) ]*17 + wy*4+quad; ~2-way banks.
        #pragma unroll
        for (int ni = 0; ni < 4; ++ni) {
            const int jl = wx * 64 + ni * 16 + l15;
            #pragma unroll
            for (int c = 0; c < 5; ++c)
                scr[(size_t)(c * 128 + jl) * 17 + (wy << 2) + quad] = cst[ni][c];
        }
        __syncthreads();
        for (int o = tid; o < 640; o += 512) {
            const int c = o >> 7, j = o & 127;
            const float* p = scr + (size_t)(c * 128 + j) * 17;
            float s = (((p[0] + p[1]) + (p[2] + p[3])) + ((p[4] + p[5]) + (p[6] + p[7])))
                    + (((p[8] + p[9]) + (p[10] + p[11])) + ((p[12] + p[13]) + (p[14] + p[15])));
            unsafeAtomicAdd(&acc5[(size_t)c * NB + (j0 + j)], s);
        }
    }

    // ---- last-block fold: per-row corr from acc5 + upart -> out
    __shared__ int lastFlag;
    __syncthreads();                           // all threads' atomics issued+drained
    if (tid == 0) {
        __threadfence();                       // our adds visible device-wide
        lastFlag = (atomicAdd(cnt, 1u) == (unsigned)(NBLK - 1));
    }
    __syncthreads();
    if (lastFlag) {
        __threadfence();                       // acquire all blocks' atomic adds
        const float invN = 1.0f / (float)NB;
        float v = 0.f;
        #pragma unroll
        for (int rr = 0; rr < 8; ++rr) {
            const int r = tid + rr * 512;
            const float a  = acc5[0 * NB + r];
            const float b  = acc5[1 * NB + r];
            const float c2 = acc5[2 * NB + r];
            const float d  = acc5[3 * NB + r];
            const float e  = acc5[4 * NB + r];
            float num = e - a * c2 * invN;
            float vh  = fmaxf(b - a * a * invN, 0.f);
            float vl  = fmaxf(d - c2 * c2 * invN, 0.f);
            v += num / (sqrtf(vh) * sqrtf(vl));
        }
        v *= (-BETA_C * invN);
        if (tid < 96) v += upart[tid] * (ALPHA_C / (float)NTOT);
        #pragma unroll
        for (int off = 32; off; off >>= 1) v += __shfl_down(v, off, 64);
        float* fin = (float*)smem;             // scr free here
        __syncthreads();
        if ((tid & 63) == 0) fin[tid >> 6] = v;
        __syncthreads();
        if (tid == 0)
            out[0] = ((fin[0] + fin[1]) + (fin[2] + fin[3]))
                   + ((fin[4] + fin[5]) + (fin[6] + fin[7]));
    }
}

extern "C" void kernel_launch(void* const* d_in, const int* in_sizes, int n_in,
                              void* d_out, int out_size, void* d_ws, size_t ws_size,
                              hipStream_t stream) {
    const float* emb  = (const float*)d_in[0];   // (4096, 32) f32
    const float* ph   = (const float*)d_in[1];   // (4096, 784) f32
    const int*   perm = (const int*)d_in[2];     // (20480,) i32
    float* out = (float*)d_out;

    char* ws = (char*)d_ws;
    unsigned char* Xf8 = (unsigned char*)(ws + WS_XF8);
    bf16*  Ebf    = (bf16*) (ws + WS_EBF);
    float* sqx    = (float*)(ws + WS_SQX);
    float* sqe    = (float*)(ws + WS_SQE);
    float* acc5   = (float*)(ws + WS_ACC5);
    float* upart  = (float*)(ws + WS_UPART);
    unsigned* cnt = (unsigned*)(ws + WS_CNT);

    prep_fused<<<1120, 256, 0, stream>>>(ph, emb, perm, Xf8, sqx, Ebf, sqe, upart, acc5, cnt);
    gram_kernel<<<NBLK, 512, 0, stream>>>(Xf8, Ebf, sqx, sqe, acc5, upart, cnt, out);
}

// Round 11
// 107.585 us; speedup vs baseline: 1.2273x; 1.0041x over previous
//
#include <hip/hip_runtime.h>
#include <hip/hip_bf16.h>
#include <math.h>

// Problem constants
#define NB    4096
#define DH    784
#define NSR   5
#define NNEG  (NB*NSR)       // 20480
#define NTOT  (NB + NNEG)    // 24576

#define A_CONST 1.576943f
#define PEXP    1.7901216f   // 2*B_PARAM
#define EPS_C   1.0e-4f
#define ALPHA_C 0.9296875f   // BATCH_COUNT=500: beta=0.5*(1-500/800)^2=0.0703125
#define BETA_C  0.0703125f

#define NBLK  528            // upper-triangular 32x32 block grid (8*66)
#define CH    262144         // K-chunk stride in XT layout: 4096 rows x 64 B
#define SBUF  32768          // LDS stage buffer: [A0 8K|A1 8K|B0 8K|B1 8K]

typedef __hip_bfloat16 bf16;
typedef short bf16x8 __attribute__((ext_vector_type(8)));
typedef float f32x4  __attribute__((ext_vector_type(4)));
typedef float f32x2  __attribute__((ext_vector_type(2)));
typedef long long2v __attribute__((ext_vector_type(2)));

// Workspace layout (bytes)
#define WS_XF8    0                      // 13*4096*64 = 3407872 (K-MAJOR: XT[c][row][64B])
#define WS_EBF    3407872                // 4096*32*2  = 262144
#define WS_SQX    3670016                // 4096*4     = 16384
#define WS_SQE    3686400                // 4096*4     = 16384
#define WS_ACC5   3702784                // 5*4096*4   = 81920  (atomic accumulators)
#define WS_UPART  8945664                // 96*4       = 384
#define WS_CNT    8946304                // 4

__device__ __forceinline__ void gl2lds16(const void* g, void* l) {
    __builtin_amdgcn_global_load_lds(
        (const __attribute__((address_space(1))) unsigned int*)g,
        (__attribute__((address_space(3))) unsigned int*)l,
        16, 0, 0);
}

// ---- fused prep: blocks 0..1023 -> X cast to fp8-e4m3, K-MAJOR layout
// XT[c][row][p]: dword index c*65536 + row*16 + p  (c=0..12 K-chunks, p=0..15).
// Within a chunk the 16 dwords keep the COLUMN-PERMUTED order: dword p
// sources src float4 c*16 + h*8 + q*2 + w, q=p>>2, h=(p>>1)&1, w=p&1.
// blocks 1024..1119 -> UMAP CE partials + e_to bf16 prep + zero acc5/cnt
__global__ void prep_fused(const float* __restrict__ X, const float* __restrict__ emb,
                           const int* __restrict__ perm, unsigned char* __restrict__ Xf8,
                           float* __restrict__ sqx, bf16* __restrict__ Ebf,
                           float* __restrict__ sqe, float* __restrict__ upart,
                           float* __restrict__ acc5, unsigned* __restrict__ cnt) {
    if (blockIdx.x == 0 && threadIdx.x == 0) *cnt = 0u;   // for gram last-block
    if (blockIdx.x < 1024) {
        const int wave = threadIdx.x >> 6, lane = threadIdx.x & 63;
        const int row = blockIdx.x * 4 + wave;
        const float4* xr = (const float4*)(X + (size_t)row * DH);
        int* xb = (int*)Xf8;
        float s = 0.f;
        #pragma unroll
        for (int it = 0; it < 4; ++it) {
            const int idx = lane + it * 64;   // dword 0..207
            if (idx < 208) {
                const int c = idx >> 4, p = idx & 15;
                const int q = p >> 2, h = (p >> 1) & 1, w = p & 1;
                const int src = c * 16 + h * 8 + q * 2 + w;
                int pk = 0;
                if (src < 196) {
                    float4 v = xr[src];
                    s += v.x * v.x + v.y * v.y + v.z * v.z + v.w * v.w;
                    int lo = __builtin_amdgcn_cvt_pk_fp8_f32(v.x, v.y, 0, false);
                    pk = __builtin_amdgcn_cvt_pk_fp8_f32(v.z, v.w, lo, true);
                }
                xb[(size_t)c * 65536 + (size_t)row * 16 + p] = pk;   // K-major
            }
        }
        #pragma unroll
        for (int off = 32; off; off >>= 1) s += __shfl_down(s, off, 64);
        if (lane == 0) sqx[row] = s;
        return;
    }
    // UMAP CE + e_to bf16 prep + acc5 zeroing
    const int ub = blockIdx.x - 1024;
    const int t = ub * 256 + threadIdx.x;
    if (t < 5 * NB) acc5[t] = 0.f;                // zero atomic accumulators
    float val = 0.f;
    if (t < NB) {
        const float4* av = (const float4*)(emb + (size_t)t * 32);
        float4 t0 = av[0], t1 = av[1], t2 = av[2], t3 = av[3];   // e_to
        float4 f0 = av[4], f1 = av[5], f2 = av[6], f3 = av[7];   // e_from
        bf16* eb = Ebf + (size_t)t * 32;
        union { bf16 h[4]; ushort4 u; } cv;
        #define ST4(dst, q) cv.h[0]=__float2bfloat16(q.x); cv.h[1]=__float2bfloat16(q.y); \
                            cv.h[2]=__float2bfloat16(q.z); cv.h[3]=__float2bfloat16(q.w); \
                            *(ushort4*)(dst) = cv.u;
        ST4(eb,      t0) ST4(eb + 4,  t1) ST4(eb + 8,  t2) ST4(eb + 12, t3)
        #undef ST4
        ushort4 z = {0, 0, 0, 0};
        *(ushort4*)(eb + 16) = z; *(ushort4*)(eb + 20) = z;
        *(ushort4*)(eb + 24) = z; *(ushort4*)(eb + 28) = z;
        sqe[t] = t0.x*t0.x + t0.y*t0.y + t0.z*t0.z + t0.w*t0.w
               + t1.x*t1.x + t1.y*t1.y + t1.z*t1.z + t1.w*t1.w
               + t2.x*t2.x + t2.y*t2.y + t2.z*t2.z + t2.w*t2.w
               + t3.x*t3.x + t3.y*t3.y + t3.z*t3.z + t3.w*t3.w;
        float d2 = 0.f;
        #define D2(a, b) { float4 df = {a.x-b.x, a.y-b.y, a.z-b.z, a.w-b.w}; \
                           d2 += df.x*df.x + df.y*df.y + df.z*df.z + df.w*df.w; }
        D2(t0, f0) D2(t1, f1) D2(t2, f2) D2(t3, f3)
        #undef D2
        float d = sqrtf(d2);
        float p = 1.f / (1.f + A_CONST * powf(d, PEXP));
        val = -logf(fminf(fmaxf(p, EPS_C), 1.f));
    } else if (t < NTOT) {
        const int k = t - NB;
        const int ti = k / 5;
        const int fi = perm[k] / 5;
        const float4* at = (const float4*)(emb + (size_t)ti * 32);
        const float4* bt = (const float4*)(emb + (size_t)fi * 32 + 16);
        float d2 = 0.f;
        #pragma unroll
        for (int q = 0; q < 4; ++q) {
            float4 a = at[q], b = bt[q];
            float4 df = {a.x-b.x, a.y-b.y, a.z-b.z, a.w-b.w};
            d2 += df.x*df.x + df.y*df.y + df.z*df.z + df.w*df.w;
        }
        float d = sqrtf(d2);
        float p = 1.f / (1.f + A_CONST * powf(d, PEXP));
        val = -logf(fminf(fmaxf(1.f - p, EPS_C), 1.f));
    }
    #pragma unroll
    for (int off = 32; off; off >>= 1) val += __shfl_down(val, off, 64);
    __shared__ float ps[4];
    if ((threadIdx.x & 63) == 0) ps[threadIdx.x >> 6] = val;
    __syncthreads();
    if (threadIdx.x == 0) upart[ub] = ps[0] + ps[1] + ps[2] + ps[3];
}

// ---- main: upper-triangular 128x128 fp8 X-gram.
// Round-11: HALVE THE STAGE COUNT. Measured invariant: cost per stage-
// instance is fixed at ~1.4-1.8us across every depth/barrier/residency/
// locality/transport variant, while the stage's throughput content is
// <0.6us -> the wall is a fixed per-stage convoy quantum. So: 2 K-chunks
// per stage (32KB, 4 DMAs/thread, 32 MFMA), 13 chunks + E fold into 7
// stages (stage 6 = chunk 12 + E). Stage-instances/CU: 27 -> 14.4.
// 2x32KB buffers + norms = 67.6KB (same 2 blocks/CU as round-6). 2-buffer
// dbuf needs a read-complete fence before re-staging: vmcnt(4) -> barrier
// -> ds_read -> lgkmcnt(0) -> barrier -> prefetch(t+2) -> MFMA.
// Epilogue/atomics/region-map/last-block fold byte-identical to round 6.
__global__ __launch_bounds__(512, 4) void gram_kernel(
    const unsigned char* __restrict__ Xf8, const bf16* __restrict__ Ebf,
    const float* __restrict__ sqx, const float* __restrict__ sqe,
    float* __restrict__ acc5, const float* __restrict__ upart,
    unsigned* __restrict__ cnt, float* __restrict__ out) {
    __shared__ __align__(16) unsigned char smem[67584];
    // buf b at smem + b*SBUF: [A-half0 8K | A-half1 8K | B-half0 8K | B-half1 8K]
    float* sqxs = (float*)(smem + 65536);           // 256 f: [0..127]=i, [128..255]=j
    float* sqes = (float*)(smem + 66560);           // 256 f
    float* scr  = (float*)smem;                     // epilogue scratch (<=46080 B)

    // Region-based XCD mapping (XCD = blockIdx & 7, idx = blockIdx >> 3):
    //  k<6 : square S(g,h), pairs {01,02,03,12,13,23}; idx<64 -> (g*8+idx/8,
    //        h*8+idx%8); idx 64,65 -> donated diag cell (panel in footprint).
    //  k=6 : D0 ranks 0..33 then D1 ranks 0..31; k=7 : D2 0..35 then D3 0..29.
    int bi, bj;
    {
        const int k = blockIdx.x & 7;
        const int idx = blockIdx.x >> 3;          // 0..65
        int g = -1, r = 0;
        if (k < 6) {
            const int SG[6] = {0,0,0,1,1,2}, SH[6] = {1,2,3,2,3,3};
            if (idx < 64) { bi = SG[k]*8 + (idx>>3); bj = SH[k]*8 + (idx&7); }
            else {
                const int DG[6] = {1,0,3,1,3,3};
                const int DR[6] = {32,34,30,34,32,34};
                g = DG[k]; r = DR[k] + (idx - 64);
            }
        } else if (k == 6) {
            if (idx < 34) { g = 0; r = idx; } else { g = 1; r = idx - 34; }
        } else {
            if (idx < 36) { g = 2; r = idx; } else { g = 3; r = idx - 36; }
        }
        if (g >= 0) {   // unrank within 8x8 upper triangle (incl diagonal)
            int a = 0;
            while (r >= 8 - a) { r -= 8 - a; ++a; }
            bi = g * 8 + a; bj = g * 8 + a + r;
        }
    }
    const int i0 = bi * 128, j0 = bj * 128;

    const int tid  = threadIdx.x;
    const int wave = tid >> 6;
    const int lane = tid & 63;
    const int wy = wave >> 1, wx = wave & 1;        // wy 0..3: 32-row strip; wx 0..1: 64-col half
    const int quad = lane >> 4, l15 = lane & 15;

    f32x4 acc[2][4];
    #pragma unroll
    for (int a = 0; a < 2; ++a)
        #pragma unroll
        for (int b = 0; b < 4; ++b)
            acc[a][b] = (f32x4){0.f, 0.f, 0.f, 0.f};

    // staging: wave w stages rows [w*16, w*16+16) of A and B for BOTH chunks
    // of the stage. lane L: row w*16 + (L>>2); 16-B seg (L&3)^((L>>3)&3)
    // (pre-swizzled source, linear LDS dest). K-major: 1KB contiguous/DMA.
    const int rA  = lane >> 2;
    const int gsb = (((lane & 3) ^ ((lane >> 3) & 3))) * 16;
    const unsigned char* gA = Xf8 + (size_t)(i0 + wave * 16 + rA) * 64 + gsb;
    const unsigned char* gB = Xf8 + (size_t)(j0 + wave * 16 + rA) * 64 + gsb;
    const unsigned char* eA = (const unsigned char*)Ebf + (size_t)(i0 + wave * 16 + rA) * 64 + gsb;
    const unsigned char* eB = (const unsigned char*)Ebf + (size_t)(j0 + wave * 16 + rA) * 64 + gsb;

    // sq-norm staging FIRST, then one full __syncthreads (its vmcnt(0) drain
    // happens before any DMA is in flight).
    if (tid < 128) {
        sqxs[tid] = sqx[i0 + tid]; sqxs[128 + tid] = sqx[j0 + tid];
        sqes[tid] = sqe[i0 + tid]; sqes[128 + tid] = sqe[j0 + tid];
    }
    __syncthreads();

    // stage s covers chunks (2s, 2s+1); stage 6 covers chunk 12 + E tiles.
#define STAGE_X(b, s) { \
        unsigned char* d = smem + (b) * SBUF + wave * 1024; \
        gl2lds16(gA + (size_t)(2 * (s)) * CH,     d); \
        gl2lds16(gA + (size_t)(2 * (s) + 1) * CH, d + 8192); \
        gl2lds16(gB + (size_t)(2 * (s)) * CH,     d + 16384); \
        gl2lds16(gB + (size_t)(2 * (s) + 1) * CH, d + 24576); }
#define STAGE_LAST(b) { \
        unsigned char* d = smem + (b) * SBUF + wave * 1024; \
        gl2lds16(gA + (size_t)12 * CH, d); \
        gl2lds16(eA,                   d + 8192); \
        gl2lds16(gB + (size_t)12 * CH, d + 16384); \
        gl2lds16(eB,                   d + 24576); }

    // prologue: stages 0,1 -> bufs 0,1 (8 DMAs/thread in flight)
    STAGE_X(0, 0)
    STAGE_X(1, 1)

    // fragment byte offset: 16B = [h0 8B | h1 8B] for this lane's quad
    // (column-permuted layout), at swizzled position quad^key.
    const int key = (l15 >> 1) & 3;
    const int boX = ((quad ^ key) << 4);
    const int aro = (wy * 32 + l15) * 64 + boX;     // A-frag row offset base
    const int bro = (wx * 64 + l15) * 64 + boX;     // B-frag row offset base

    #pragma unroll
    for (int t = 0; t < 7; ++t) {
        // retire stage t's 4 DMAs (leave stage t+1's 4 in flight); t==6: drain.
        if (t < 6) { asm volatile("s_waitcnt vmcnt(4)" ::: "memory"); }
        else       { asm volatile("s_waitcnt vmcnt(0)" ::: "memory"); }
        __builtin_amdgcn_s_barrier();
        const unsigned char* bb = smem + (t & 1) * SBUF;
        long2v aF0[2], bF0[4], aF1[2], bF1[4];
        #pragma unroll
        for (int mi = 0; mi < 2; ++mi)
            aF0[mi] = *(const long2v*)&bb[aro + mi * 1024];
        #pragma unroll
        for (int ni = 0; ni < 4; ++ni)
            bF0[ni] = *(const long2v*)&bb[16384 + bro + ni * 1024];
        if (t < 6) {
            #pragma unroll
            for (int mi = 0; mi < 2; ++mi)
                aF1[mi] = *(const long2v*)&bb[8192 + aro + mi * 1024];
            #pragma unroll
            for (int ni = 0; ni < 4; ++ni)
                bF1[ni] = *(const long2v*)&bb[24576 + bro + ni * 1024];
        }
        if (t < 5) {
            // reads of buf[t&1] complete before re-staging it with stage t+2
            asm volatile("s_waitcnt lgkmcnt(0)" ::: "memory");
            __builtin_amdgcn_s_barrier();
            if (t < 4) { STAGE_X(t & 1, t + 2) }
            else       { STAGE_LAST(0) }          // stage 6 -> buf 0 (= 6&1)
        }
        #pragma unroll
        for (int mi = 0; mi < 2; ++mi)
            #pragma unroll
            for (int ni = 0; ni < 4; ++ni) {
                acc[mi][ni] = __builtin_amdgcn_mfma_f32_16x16x32_fp8_fp8(
                    aF0[mi][0], bF0[ni][0], acc[mi][ni], 0, 0, 0);
                acc[mi][ni] = __builtin_amdgcn_mfma_f32_16x16x32_fp8_fp8(
                    aF0[mi][1], bF0[ni][1], acc[mi][ni], 0, 0, 0);
            }
        if (t < 6) {
            #pragma unroll
            for (int mi = 0; mi < 2; ++mi)
                #pragma unroll
                for (int ni = 0; ni < 4; ++ni) {
                    acc[mi][ni] = __builtin_amdgcn_mfma_f32_16x16x32_fp8_fp8(
                        aF1[mi][0], bF1[ni][0], acc[mi][ni], 0, 0, 0);
                    acc[mi][ni] = __builtin_amdgcn_mfma_f32_16x16x32_fp8_fp8(
                        aF1[mi][1], bF1[ni][1], acc[mi][ni], 0, 0, 0);
                }
        }
    }
#undef STAGE_X
#undef STAGE_LAST

    // E fragments from buf0 halves 1 (A) and 3 (B); j-side norms from LDS.
    bf16x8 afE[2], bfrE[4];
    #pragma unroll
    for (int mi = 0; mi < 2; ++mi)
        afE[mi] = *(const bf16x8*)&smem[8192 + aro + mi * 1024];
    #pragma unroll
    for (int ni = 0; ni < 4; ++ni)
        bfrE[ni] = *(const bf16x8*)&smem[24576 + bro + ni * 1024];
    float sqxj[4], sqej[4];
    #pragma unroll
    for (int ni = 0; ni < 4; ++ni) {
        const int jl = wx * 64 + ni * 16 + l15;
        sqxj[ni] = sqxs[128 + jl]; sqej[ni] = sqes[128 + jl];
    }
    __syncthreads();   // all waves done reading E tiles -> scratch region free

    // C/D layout: col = lane&15, row = quad*4 + reg  [m89/m91]
    float cst[4][5];   // col partials per ni: {H, H2, L, L2, HL}, both mi
    #pragma unroll
    for (int ni = 0; ni < 4; ++ni)
        #pragma unroll
        for (int c = 0; c < 5; ++c) cst[ni][c] = 0.f;

    #pragma unroll
    for (int mi = 0; mi < 2; ++mi) {
        f32x4 aE[4];
        #pragma unroll
        for (int ni = 0; ni < 4; ++ni) {
            f32x4 z = (f32x4){0.f, 0.f, 0.f, 0.f};
            aE[ni] = __builtin_amdgcn_mfma_f32_16x16x32_bf16(afE[mi], bfrE[ni], z, 0, 0, 0);
        }
        const int ilb = wy * 32 + mi * 16 + quad * 4;
        float sqxi[4], sqei[4];
        #pragma unroll
        for (int r = 0; r < 4; ++r) { sqxi[r] = sqxs[ilb + r]; sqei[r] = sqes[ilb + r]; }
        float rs[5][4];
        #pragma unroll
        for (int c = 0; c < 5; ++c)
            #pragma unroll
            for (int r = 0; r < 4; ++r) rs[c][r] = 0.f;
        #pragma unroll
        for (int ni = 0; ni < 4; ++ni) {
            const int j = j0 + wx * 64 + ni * 16 + l15;
            #pragma unroll
            for (int r = 0; r < 4; ++r) {
                const int i = i0 + ilb + r;
                float H, L;
                if (i == j) { H = 0.f; L = 0.f; }
                else {
                    float d2  = sqxi[r] + sqxj[ni] - 2.0f * acc[mi][ni][r];
                    H = sqrtf(fmaxf(d2, 0.f));
                    float d2e = sqei[r] + sqej[ni] - 2.0f * aE[ni][r];
                    L = sqrtf(fmaxf(d2e, 0.f));
                }
                rs[0][r] += H; rs[1][r] += H * H; rs[2][r] += L;
                rs[3][r] += L * L; rs[4][r] += H * L;
                cst[ni][0] += H; cst[ni][1] += H * H; cst[ni][2] += L;
                cst[ni][3] += L * L; cst[ni][4] += H * L;
            }
        }
        // dump row partials: [ (wx*5+c)*64 + li ]*18 + l15, li = wy*16+quad*4+r.
        // write banks: (72*quad + l15) & 31 = (8q+l15)&31 -> 2-way (free).
        #pragma unroll
        for (int c = 0; c < 5; ++c)
            #pragma unroll
            for (int r = 0; r < 4; ++r)
                scr[(size_t)((((wx * 5 + c) << 6) + (wy << 4) + (quad << 2) + r)) * 18 + l15]
                    = rs[c][r];
        __syncthreads();
        // cooperative 16-wide reduce over BOTH wx halves -> one atomic per elem
        for (int o = tid; o < 320; o += 512) {
            const int c = o >> 6, li = o & 63;
            const float* p0 = scr + (size_t)((c << 6) + li) * 18;          // wx=0
            const float* p1 = scr + (size_t)(((5 + c) << 6) + li) * 18;    // wx=1
            float s = 0.f;
            #pragma unroll
            for (int k = 0; k < 16; k += 2) {
                f32x2 v0 = *(const f32x2*)&p0[k]; s += v0.x + v0.y;
                f32x2 v1 = *(const f32x2*)&p1[k]; s += v1.x + v1.y;
            }
            const int iloc = ((li >> 4) << 5) + mi * 16 + (li & 15);
            unsafeAtomicAdd(&acc5[(size_t)c * NB + (i0 + iloc)], s);
        }
        __syncthreads();
    }

    if (bi != bj) {
        // dump col partials: [ (c*128 + j) ]*17 + wy*4+quad; ~2-way banks.
        #pragma unroll
        for (int ni = 0; ni < 4; ++ni) {
            const int jl = wx * 64 + ni * 16 + l15;
            #pragma unroll
            for (int c = 0; c < 5; ++c)
                scr[(size_t)(c * 128 + jl) * 17 + (wy << 2) + quad] = cst[ni][c];
        }
        __syncthreads();
        for (int o = tid; o < 640; o += 512) {
            const int c = o >> 7, j = o & 127;
            const float* p = scr + (size_t)(c * 128 + j) * 17;
            float s = (((p[0] + p[1]) + (p[2] + p[3])) + ((p[4] + p[5]) + (p[6] + p[7])))
                    + (((p[8] + p[9]) + (p[10] + p[11])) + ((p[12] + p[13]) + (p[14] + p[15])));
            unsafeAtomicAdd(&acc5[(size_t)c * NB + (j0 + j)], s);
        }
    }

    // ---- last-block fold: per-row corr from acc5 + upart -> out
    __shared__ int lastFlag;
    __syncthreads();                           // all threads' atomics issued+drained
    if (tid == 0) {
        __threadfence();                       // our adds visible device-wide
        lastFlag = (atomicAdd(cnt, 1u) == (unsigned)(NBLK - 1));
    }
    __syncthreads();
    if (lastFlag) {
        __threadfence();                       // acquire all blocks' atomic adds
        const float invN = 1.0f / (float)NB;
        float v = 0.f;
        #pragma unroll
        for (int rr = 0; rr < 8; ++rr) {
            const int r = tid + rr * 512;
            const float a  = acc5[0 * NB + r];
            const float b  = acc5[1 * NB + r];
            const float c2 = acc5[2 * NB + r];
            const float d  = acc5[3 * NB + r];
            const float e  = acc5[4 * NB + r];
            float num = e - a * c2 * invN;
            float vh  = fmaxf(b - a * a * invN, 0.f);
            float vl  = fmaxf(d - c2 * c2 * invN, 0.f);
            v += num / (sqrtf(vh) * sqrtf(vl));
        }
        v *= (-BETA_C * invN);
        if (tid < 96) v += upart[tid] * (ALPHA_C / (float)NTOT);
        #pragma unroll
        for (int off = 32; off; off >>= 1) v += __shfl_down(v, off, 64);
        float* fin = (float*)smem;             // scr free here
        __syncthreads();
        if ((tid & 63) == 0) fin[tid >> 6] = v;
        __syncthreads();
        if (tid == 0)
            out[0] = ((fin[0] + fin[1]) + (fin[2] + fin[3]))
                   + ((fin[4] + fin[5]) + (fin[6] + fin[7]));
    }
}

extern "C" void kernel_launch(void* const* d_in, const int* in_sizes, int n_in,
                              void* d_out, int out_size, void* d_ws, size_t ws_size,
                              hipStream_t stream) {
    const float* emb  = (const float*)d_in[0];   // (4096, 32) f32
    const float* ph   = (const float*)d_in[1];   // (4096, 784) f32
    const int*   perm = (const int*)d_in[2];     // (20480,) i32
    float* out = (float*)d_out;

    char* ws = (char*)d_ws;
    unsigned char* Xf8 = (unsigned char*)(ws + WS_XF8);
    bf16*  Ebf    = (bf16*) (ws + WS_EBF);
    float* sqx    = (float*)(ws + WS_SQX);
    float* sqe    = (float*)(ws + WS_SQE);
    float* acc5   = (float*)(ws + WS_ACC5);
    float* upart  = (float*)(ws + WS_UPART);
    unsigned* cnt = (unsigned*)(ws + WS_CNT);

    prep_fused<<<1120, 256, 0, stream>>>(ph, emb, perm, Xf8, sqx, Ebf, sqe, upart, acc5, cnt);
    gram_kernel<<<NBLK, 512, 0, stream>>>(Xf8, Ebf, sqx, sqe, acc5, upart, cnt, out);
}